// Round 1
// baseline (181.007 us; speedup 1.0000x reference)
//
#include <hip/hip_runtime.h>
#include <math.h>

#define DD 128
#define NSRC 8
#define EMAX 32          // 32*64 = 2048 >= (m+1)(m+2)/2  ->  m <= 62 fast path
#define MFAST 62
#define LOG_2PI 1.83787706640934548356f
#define LN2F 0.69314718055994531f
#define EPSF 1e-6f

// e -> row index within a packed lower triangle (row r has r+1 elements).
__device__ inline int tri_row_of(int e) {
    float f = sqrtf(8.f * (float)e + 1.f);
    int r = (int)((f - 1.f) * 0.5f);
    if ((r + 1) * (r + 2) / 2 <= e) ++r;
    else if (r * (r + 1) / 2 > e) --r;
    return r;
}

// ---------------------------------------------------------------------------
// K1: fused  (a) miss_mask layout detect -> flagarr[block]  (b) Q_s
//            (c) ldS[s]  (d) block 0 zeroes partial/ovf_cnt      (verified)
// ---------------------------------------------------------------------------
__global__ __launch_bounds__(128) void k_precompute(
    const float* __restrict__ W, const float* __restrict__ ls2,
    const unsigned int* __restrict__ mw, int n_words,
    float* __restrict__ Q, float* __restrict__ ldS,
    int* __restrict__ flagarr, float* __restrict__ partial,
    int* __restrict__ ovf_cnt)
{
    __shared__ float Bs[DD][DD + 1];
    __shared__ float r[4][DD + 1];
    __shared__ float sinv[DD];
    __shared__ float part2[2];
    __shared__ int fsh[2];
    const int tid = threadIdx.x;
    const int s   = blockIdx.x >> 5;
    const int i0  = (blockIdx.x & 31) * 4;

    if (blockIdx.x == 0) {
        if (tid < 64)  partial[tid] = 0.f;
        if (tid == 64) *ovf_cnt = 0;
    }

    int gid = (blockIdx.x * 128 + tid) * 4;
    int f = 0;
    #pragma unroll
    for (int t = 0; t < 4; ++t) {
        int idx = gid + t;
        if (idx < n_words) {
            unsigned int v = mw[idx];
            if (v > 1u) f |= 1;
            if (v == 0x3F800000u) f |= 2;
        }
    }
    unsigned long long bA = __ballot(f & 1);
    unsigned long long bB = __ballot(f & 2);
    if ((tid & 63) == 0) fsh[tid >> 6] = (bA ? 1 : 0) | (bB ? 2 : 0);

    for (int idx = tid; idx < DD * DD; idx += 128) {
        int row = idx >> 7, col = idx & 127;
        Bs[row][col] = (row == col ? 1.f : 0.f) - W[idx];
    }
    sinv[tid] = 1.f / fmaxf(expf(ls2[s * DD + tid]), EPSF);
    __syncthreads();
    if (tid == 0) flagarr[blockIdx.x] = fsh[0] | fsh[1];
    for (int a = 0; a < 4; ++a)
        r[a][tid] = Bs[i0 + a][tid] * sinv[tid];
    __syncthreads();

    const int j = tid;
    float acc0 = 0.f, acc1 = 0.f, acc2 = 0.f, acc3 = 0.f;
    #pragma unroll 4
    for (int d = 0; d < DD; ++d) {
        float bj = Bs[j][d];
        acc0 += r[0][d] * bj;
        acc1 += r[1][d] * bj;
        acc2 += r[2][d] * bj;
        acc3 += r[3][d] * bj;
    }
    size_t base = ((size_t)s * DD + i0) * DD + j;
    Q[base         ] = acc0;
    Q[base +     DD] = acc1;
    Q[base + 2 * DD] = acc2;
    Q[base + 3 * DD] = acc3;

    if (i0 == 0) {
        float v = logf(fmaxf(expf(ls2[s * DD + tid]), EPSF));
        for (int o = 32; o; o >>= 1) v += __shfl_down(v, o, 64);
        if ((tid & 63) == 0) part2[tid >> 6] = v;
        __syncthreads();
        if (tid == 0) ldS[s] = part2[0] + part2[1];
    }
}

// ---------------------------------------------------------------------------
// K2 fast: ONE WAVE per TWO SAMPLES (A,B), lock-step interleaved.
// Rationale (R14): k_fast was latency-bound (VALUBusy 22%, occ 22%, HBM 0.7%);
// the ~38-step serial Cholesky chain left each wave ~98% stalled with only
// 16 grid-limited waves/CU. Interleaving two independent samples per wave
// halves per-sample serial latency at ~constant instruction issue.
// ---------------------------------------------------------------------------
__global__ __launch_bounds__(64, 2) void k_fast(
    const float* __restrict__ data, const float* __restrict__ mu,
    const float* __restrict__ wgt, const int* __restrict__ src,
    const void* __restrict__ miss, const int* __restrict__ flagarr,
    const float* __restrict__ Q, const float* __restrict__ ldS,
    float* __restrict__ partial, int* __restrict__ ovf_cnt,
    int* __restrict__ ovf_list, int n)
{
    __shared__ float xshA[DD], xshB[DD];
    __shared__ float yshA[DD], yshB[DD];
    __shared__ int   midxA[64], midxB[64];
    __shared__ float cscA[2][64], cscB[2][64];

    const int lane = threadIdx.x;
    const int iA = blockIdx.x * 2;
    const bool validB = (iA + 1) < n;
    const int iB = validB ? (iA + 1) : iA;
    const int sA = src[iA], sB = src[iB];
    const float* QA = Q + (size_t)sA * DD * DD;
    const float* QB = Q + (size_t)sB * DD * DD;
    const size_t baseA = (size_t)iA * DD;
    const size_t baseB = (size_t)iB * DD;
    const int j0 = 2 * lane, j1 = 2 * lane + 1;

    // ---- layout flag: OR-reduce flagarr[256] (written by prior dispatch) ----
    int fl = 0;
    #pragma unroll
    for (int t = 0; t < 4; ++t) fl |= flagarr[lane + 64 * t];
    unsigned long long fb1 = __ballot(fl & 1);
    unsigned long long fb2 = __ballot(fl & 2);
    const int f = (fb1 ? 1 : 0) | (fb2 ? 2 : 0);

    // ---- mask decode for both samples (uniform branch on detected layout) ----
    bool mAe, mAo, mBe, mBo;
    if (f & 2) {
        const float* M = (const float*)miss;
        mAe = M[baseA + j0] != 0.f;  mAo = M[baseA + j1] != 0.f;
        mBe = M[baseB + j0] != 0.f;  mBo = M[baseB + j1] != 0.f;
    } else if (f & 1) {
        const unsigned char* M = (const unsigned char*)miss;
        mAe = M[baseA + j0] != 0;    mAo = M[baseA + j1] != 0;
        mBe = M[baseB + j0] != 0;    mBo = M[baseB + j1] != 0;
    } else {
        const int* M = (const int*)miss;
        mAe = M[baseA + j0] != 0;    mAo = M[baseA + j1] != 0;
        mBe = M[baseB + j0] != 0;    mBo = M[baseB + j1] != 0;
    }

    unsigned long long bAE = __ballot(mAe), bAO = __ballot(mAo);
    unsigned long long bBE = __ballot(mBe), bBO = __ballot(mBo);
    const int mAr = __popcll(bAE) + __popcll(bAO);
    const int mBr = __popcll(bBE) + __popcll(bBO);
    const bool skipA = (mAr > MFAST);
    const bool skipB = (mBr > MFAST) || !validB;
    if (lane == 0) {
        if (skipA)                    { int pos = atomicAdd(ovf_cnt, 1); ovf_list[pos] = iA; }
        if (validB && (mBr > MFAST))  { int pos = atomicAdd(ovf_cnt, 1); ovf_list[pos] = iB; }
    }
    const int mA = skipA ? 0 : mAr;
    const int mB = skipB ? 0 : mBr;
    unsigned long long lt = (1ull << lane) - 1ull;
    if (!skipA) {
        if (mAe) midxA[__popcll(bAE & lt)] = j0;
        if (mAo) midxA[__popcll(bAE) + __popcll(bAO & lt)] = j1;
    }
    if (!skipB) {
        if (mBe) midxB[__popcll(bBE & lt)] = j0;
        if (mBo) midxB[__popcll(bBE) + __popcll(bBO & lt)] = j1;
    }

    float xA0 = mAe ? 0.f : (data[baseA + j0] - mu[j0]);
    float xA1 = mAo ? 0.f : (data[baseA + j1] - mu[j1]);
    float xB0 = mBe ? 0.f : (data[baseB + j0] - mu[j0]);
    float xB1 = mBo ? 0.f : (data[baseB + j1] - mu[j1]);
    xshA[j0] = xA0;  xshA[j1] = xA1;
    xshB[j0] = xB0;  xshB[j1] = xB1;
    __syncthreads();

    // ---- y = Qx by columns, both samples interleaved (branchless float2) ----
    float yA0 = 0.f, yA1 = 0.f, zA0 = 0.f, zA1 = 0.f;
    float yB0 = 0.f, yB1 = 0.f, zB0 = 0.f, zB1 = 0.f;
    #pragma unroll 4
    for (int k = 0; k < DD; k += 2) {
        float xkA0 = xshA[k], xkA1 = xshA[k + 1];
        float xkB0 = xshB[k], xkB1 = xshB[k + 1];
        float2 qa = *(const float2*)(QA + (size_t)k * DD + j0);
        float2 qb = *(const float2*)(QA + (size_t)(k + 1) * DD + j0);
        float2 qc = *(const float2*)(QB + (size_t)k * DD + j0);
        float2 qd = *(const float2*)(QB + (size_t)(k + 1) * DD + j0);
        yA0 += xkA0 * qa.x;  yA1 += xkA0 * qa.y;
        zA0 += xkA1 * qb.x;  zA1 += xkA1 * qb.y;
        yB0 += xkB0 * qc.x;  yB1 += xkB0 * qc.y;
        zB0 += xkB1 * qd.x;  zB1 += xkB1 * qd.y;
    }
    yA0 += zA0;  yA1 += zA1;  yB0 += zB0;  yB1 += zB1;
    yshA[j0] = yA0;  yshA[j1] = yA1;
    yshB[j0] = yB0;  yshB[j1] = yB1;
    float pA = xA0 * yA0 + xA1 * yA1;
    float pB = xB0 * yB0 + xB1 * yB1;
    for (int o = 32; o; o >>= 1) {
        pA += __shfl_down(pA, o, 64);
        pB += __shfl_down(pB, o, 64);
    }
    __syncthreads();   // ysh, midx ready

    // ---- fill register slots directly from Q, both samples per t-slot ----
    const int cntTA = ((mA + 1) * (mA + 2)) >> 1;
    const int cntTB = ((mB + 1) * (mB + 2)) >> 1;
    const int cntMax = cntTA > cntTB ? cntTA : cntTB;
    unsigned keyA[EMAX], keyB[EMAX];
    float    valA[EMAX], valB[EMAX];
    #pragma unroll
    for (int t = 0; t < EMAX; ++t) {
        keyA[t] = 0u; valA[t] = 0.f;
        keyB[t] = 0u; valB[t] = 0.f;
        int e = lane + (t << 6);
        if (e < cntMax) {
            int q  = tri_row_of(e);                 // shared between A and B
            int eq = e - ((q * (q + 1)) >> 1);
            if (e < cntTA) {
                int jc = mA - q;
                int ir = jc + eq;
                float v;
                if (ir == mA) v = (jc == mA) ? 0.f : yshA[midxA[jc]];
                else          v = QA[(size_t)(midxA[ir] * DD + midxA[jc])];
                keyA[t] = ((unsigned)jc << 8) | (unsigned)ir;
                valA[t] = v;
                if (jc == 0) cscA[0][ir] = v;
            }
            if (e < cntTB) {
                int jc = mB - q;
                int ir = jc + eq;
                float v;
                if (ir == mB) v = (jc == mB) ? 0.f : yshB[midxB[jc]];
                else          v = QB[(size_t)(midxB[ir] * DD + midxB[jc])];
                keyB[t] = ((unsigned)jc << 8) | (unsigned)ir;
                valB[t] = v;
                if (jc == 0) cscB[0][ir] = v;
            }
        }
    }
    __syncthreads();

    // ---- wave-synchronous factorization: one barrier per step, 2 samples ----
    float logA = 0.f, logB = 0.f;
    const int mMax = mA > mB ? mA : mB;
    #pragma unroll 1
    for (int k = 0; k < mMax; ++k) {
        const int pb = k & 1;
        float dkA = cscA[pb][k];
        float dkB = cscB[pb][k];
        float invdA = __builtin_amdgcn_rcpf(dkA);
        float invdB = __builtin_amdgcn_rcpf(dkB);
        if (k < mA) logA += __log2f(dkA);          // mA/mB wave-uniform
        if (k < mB) logB += __log2f(dkB);
        const unsigned b1 = (unsigned)(k + 1) << 8;   // alive: key >= b1
        const unsigned b2 = (unsigned)(k + 2) << 8;   // write: key <  b2
        #pragma unroll
        for (int t = 0; t < EMAX; ++t) {
            bool aA = (keyA[t] >= b1);              // self-terminates for k>=m
            bool aB = (keyB[t] >= b1);
            if (!__any(aA | aB)) break;
            if (aA) {
                int ir = (int)(keyA[t] & 255u);
                int jc = (int)(keyA[t] >> 8);
                float ci = cscA[pb][ir];
                float cj = cscA[pb][jc];
                valA[t] -= ci * cj * invdA;
                if (keyA[t] < b2) cscA[pb ^ 1][ir] = valA[t];
            }
            if (aB) {
                int ir = (int)(keyB[t] & 255u);
                int jc = (int)(keyB[t] >> 8);
                float ci = cscB[pb][ir];
                float cj = cscB[pb][jc];
                valB[t] -= ci * cj * invdB;
                if (keyB[t] < b2) cscB[pb ^ 1][ir] = valB[t];
            }
        }
        __syncthreads();
    }

    if (lane == 0) {
        if (!skipA) {
            float llA = -0.5f * ((pA + valA[0]) + logA * LN2F + ldS[sA]
                                 + (float)(DD - mA) * LOG_2PI);
            atomicAdd(&partial[iA & 63], llA * wgt[iA]);
        }
        if (!skipB) {
            float llB = -0.5f * ((pB + valB[0]) + logB * LN2F + ldS[sB]
                                 + (float)(DD - mB) * LOG_2PI);
            atomicAdd(&partial[iB & 63], llB * wgt[iB]);
        }
    }
}

// ---------------------------------------------------------------------------
// K tail: single block. (a) drain overflow list (m > MFAST; ~always empty)
// with the verified LDS-triangle Cholesky, (b) reduce partial -> out.
// ---------------------------------------------------------------------------
__global__ __launch_bounds__(128) void k_tail(
    const float* __restrict__ data, const float* __restrict__ mu,
    const float* __restrict__ wgt, const int* __restrict__ src,
    const void* __restrict__ miss, const int* __restrict__ flagarr,
    const float* __restrict__ Q, const float* __restrict__ ldS,
    float* __restrict__ partial, const int* __restrict__ ovf_cnt,
    const int* __restrict__ ovf_list, float* __restrict__ out)
{
    __shared__ __align__(16) float xsh[DD];
    __shared__ float ysh[DD];
    __shared__ int   midx[DD];
    __shared__ float cscv[DD + 1];
    __shared__ float tri[(DD + 1) * (DD + 2) / 2];
    __shared__ float bc[2];
    __shared__ float red[2];
    __shared__ int   sh_m;
    __shared__ int   sh_f;

    const int tid = threadIdx.x;
    if (tid == 0) sh_f = 0;
    __syncthreads();
    {
        int fl = flagarr[tid] | flagarr[tid + 128];
        if (fl) atomicOr(&sh_f, fl);
    }
    __syncthreads();
    const int f = sh_f;

    const int novf = *ovf_cnt;
    for (int j = 0; j < novf; ++j) {
        const int i = ovf_list[j];
        if (tid == 0) sh_m = 0;
        __syncthreads();

        const int s = src[i];
        const float* Qs = Q + (size_t)s * DD * DD;
        const size_t g = (size_t)i * DD + tid;
        bool mm;
        if (f & 2)      mm = ((const float*)miss)[g] != 0.f;
        else if (f & 1) mm = ((const unsigned char*)miss)[g] != 0;
        else            mm = ((const int*)miss)[g] != 0;

        float xv = mm ? 0.f : (data[g] - mu[tid]);
        xsh[tid] = xv;
        if (mm) { int pos = atomicAdd(&sh_m, 1); midx[pos] = tid; }
        __syncthreads();
        const int m = sh_m;

        const float4* qrow = (const float4*)(Qs + (size_t)tid * DD);
        const float4* x4   = (const float4*)xsh;
        float acc = 0.f;
        #pragma unroll 8
        for (int d = 0; d < DD / 4; ++d) {
            float4 q = qrow[d], xx = x4[d];
            acc += q.x * xx.x + q.y * xx.y + q.z * xx.z + q.w * xx.w;
        }
        ysh[tid] = acc;
        float pp = xv * acc;
        for (int o = 32; o; o >>= 1) pp += __shfl_down(pp, o, 64);
        if ((tid & 63) == 0) red[tid >> 6] = pp;
        __syncthreads();

        const int cntA = (m * (m + 1)) >> 1;
        for (int e = tid; e < cntA; e += 128) {
            int a = tri_row_of(e);
            int b = e - ((a * (a + 1)) >> 1);
            tri[e] = Qs[(size_t)midx[a] * DD + midx[b]];
        }
        for (int b = tid; b < m; b += 128) tri[cntA + b] = ysh[midx[b]];
        if (tid == 0) tri[cntA + m] = 0.f;
        __syncthreads();

        float logacc = 0.f;
        if (m > 0) {
            if (tid == 0) {
                float d0 = tri[0];
                bc[1] = d0;
                float sq = sqrtf(d0);
                bc[0] = 1.f / sq;
                tri[0] = sq;
            }
            __syncthreads();
            for (int k = 0; k < m; ++k) {
                float inv = bc[0];
                if (tid == 0) logacc += logf(bc[1]);
                for (int ii = k + 1 + tid; ii <= m; ii += 128) {
                    int off = (ii * (ii + 1)) >> 1;
                    float v = tri[off + k] * inv;
                    tri[off + k] = v;
                    cscv[ii] = v;
                }
                __syncthreads();
                int qn  = m - k;
                int cnt = (qn * (qn + 1)) >> 1;
                for (int e = tid; e < cnt; e += 128) {
                    int ri = tri_row_of(e);
                    int rj = e - ((ri * (ri + 1)) >> 1);
                    int ii = k + 1 + ri, jj = k + 1 + rj;
                    int off = (ii * (ii + 1)) >> 1;
                    float v = tri[off + jj] - cscv[ii] * cscv[jj];
                    if (ii == jj && jj == k + 1 && k + 1 < m) {
                        bc[1] = v;
                        float sq = sqrtf(v);
                        bc[0] = 1.f / sq;
                        tri[off + jj] = sq;
                    } else {
                        tri[off + jj] = v;
                    }
                }
                __syncthreads();
            }
        }

        if (tid == 0) {
            float quad2 = (m > 0) ? -tri[cntA + m] : 0.f;
            float quad1 = red[0] + red[1];
            float ll = -0.5f * ((quad1 - quad2) + logacc + ldS[s]
                                + (float)(DD - m) * LOG_2PI);
            atomicAdd(&partial[i & 63], ll * wgt[i]);
        }
        __syncthreads();
    }

    __syncthreads();
    if (tid < 64) {
        float v = partial[tid];
        for (int o = 32; o; o >>= 1) v += __shfl_down(v, o, 64);
        if (tid == 0) out[0] = v;
    }
}

// ---------------------------------------------------------------------------
extern "C" void kernel_launch(void* const* d_in, const int* in_sizes, int n_in,
                              void* d_out, int out_size, void* d_ws, size_t ws_size,
                              hipStream_t stream)
{
    const float* data = (const float*)d_in[0];
    const float* W    = (const float*)d_in[1];
    const float* ls2  = (const float*)d_in[2];
    const float* mu   = (const float*)d_in[3];
    const float* wgt  = (const float*)d_in[4];
    const int*   src  = (const int*)d_in[5];
    const void*  miss = (const void*)d_in[6];
    float* out = (float*)d_out;

    float* Q        = (float*)d_ws;                    // 131072 floats
    float* ldS      = Q + (size_t)NSRC * DD * DD;      // 8
    float* partial  = ldS + NSRC;                      // 64
    int*   flagarr  = (int*)(partial + 64);            // 256
    int*   ovf_cnt  = flagarr + 256;                   // 1
    int*   ovf_list = ovf_cnt + 1;                     // 4096

    const int n       = in_sizes[0] / DD;              // 4096 samples
    const int n_words = (n * DD) / 4;                  // 131072

    hipLaunchKernelGGL(k_precompute, dim3(NSRC * 32), dim3(128), 0, stream,
                       W, ls2, (const unsigned int*)miss, n_words,
                       Q, ldS, flagarr, partial, ovf_cnt);
    hipLaunchKernelGGL(k_fast, dim3((n + 1) / 2), dim3(64), 0, stream,
                       data, mu, wgt, src, miss, flagarr, Q, ldS,
                       partial, ovf_cnt, ovf_list, n);
    hipLaunchKernelGGL(k_tail, dim3(1), dim3(128), 0, stream,
                       data, mu, wgt, src, miss, flagarr, Q, ldS,
                       partial, ovf_cnt, ovf_list, out);
}

// Round 2
// 162.210 us; speedup vs baseline: 1.1159x; 1.1159x over previous
//
#include <hip/hip_runtime.h>
#include <math.h>

#define DD 128
#define NSRC 8
#define EMAX 32          // 32*64 = 2048 >= (m+1)(m+2)/2  ->  m <= 62 fast path
#define MFAST 62
#define LOG_2PI 1.83787706640934548356f
#define LN2F 0.69314718055994531f
#define EPSF 1e-6f

// e -> row index within a packed lower triangle (row r has r+1 elements).
__device__ inline int tri_row_of(int e) {
    float f = sqrtf(8.f * (float)e + 1.f);
    int r = (int)((f - 1.f) * 0.5f);
    if ((r + 1) * (r + 2) / 2 <= e) ++r;
    else if (r * (r + 1) / 2 > e) --r;
    return r;
}

// ---------------------------------------------------------------------------
// K1: fused  (a) miss_mask layout detect -> flagarr[block]  (b) Q_s
//            (c) ldS[s]  (d) block 0 zeroes partial/ovf_cnt
// R15: staging was 128 scalar global loads in a non-unrolled loop (~1
// outstanding load -> latency-serialized). float4 + unroll 8 -> 8 in flight.
// ---------------------------------------------------------------------------
__global__ __launch_bounds__(128) void k_precompute(
    const float* __restrict__ W, const float* __restrict__ ls2,
    const unsigned int* __restrict__ mw, int n_words,
    float* __restrict__ Q, float* __restrict__ ldS,
    int* __restrict__ flagarr, float* __restrict__ partial,
    int* __restrict__ ovf_cnt)
{
    __shared__ float Bs[DD][DD + 1];
    __shared__ float r[4][DD + 1];
    __shared__ float sinv[DD];
    __shared__ float part2[2];
    __shared__ int fsh[2];
    const int tid = threadIdx.x;
    const int s   = blockIdx.x >> 5;
    const int i0  = (blockIdx.x & 31) * 4;

    if (blockIdx.x == 0) {
        if (tid < 64)  partial[tid] = 0.f;
        if (tid == 64) *ovf_cnt = 0;
    }

    int gid = (blockIdx.x * 128 + tid) * 4;
    int f = 0;
    #pragma unroll
    for (int t = 0; t < 4; ++t) {
        int idx = gid + t;
        if (idx < n_words) {
            unsigned int v = mw[idx];
            if (v > 1u) f |= 1;
            if (v == 0x3F800000u) f |= 2;
        }
    }
    unsigned long long bA = __ballot(f & 1);
    unsigned long long bB = __ballot(f & 2);
    if ((tid & 63) == 0) fsh[tid >> 6] = (bA ? 1 : 0) | (bB ? 2 : 0);

    // vectorized staging of B = I - W (16B/lane, 8 loads in flight)
    const float4* __restrict__ W4 = (const float4*)W;
    #pragma unroll 8
    for (int idx = tid; idx < (DD * DD) / 4; idx += 128) {
        float4 w = W4[idx];
        int row = idx >> 5;            // 32 float4 per row
        int col = (idx & 31) << 2;
        Bs[row][col + 0] = ((col + 0) == row ? 1.f : 0.f) - w.x;
        Bs[row][col + 1] = ((col + 1) == row ? 1.f : 0.f) - w.y;
        Bs[row][col + 2] = ((col + 2) == row ? 1.f : 0.f) - w.z;
        Bs[row][col + 3] = ((col + 3) == row ? 1.f : 0.f) - w.w;
    }
    sinv[tid] = 1.f / fmaxf(expf(ls2[s * DD + tid]), EPSF);
    __syncthreads();
    if (tid == 0) flagarr[blockIdx.x] = fsh[0] | fsh[1];
    for (int a = 0; a < 4; ++a)
        r[a][tid] = Bs[i0 + a][tid] * sinv[tid];
    __syncthreads();

    const int j = tid;
    float acc0 = 0.f, acc1 = 0.f, acc2 = 0.f, acc3 = 0.f;
    #pragma unroll 8
    for (int d = 0; d < DD; ++d) {
        float bj = Bs[j][d];
        acc0 += r[0][d] * bj;
        acc1 += r[1][d] * bj;
        acc2 += r[2][d] * bj;
        acc3 += r[3][d] * bj;
    }
    size_t base = ((size_t)s * DD + i0) * DD + j;
    Q[base         ] = acc0;
    Q[base +     DD] = acc1;
    Q[base + 2 * DD] = acc2;
    Q[base + 3 * DD] = acc3;

    if (i0 == 0) {
        float v = logf(fmaxf(expf(ls2[s * DD + tid]), EPSF));
        for (int o = 32; o; o >>= 1) v += __shfl_down(v, o, 64);
        if ((tid & 63) == 0) part2[tid >> 6] = v;
        __syncthreads();
        if (tid == 0) ldS[s] = part2[0] + part2[1];
    }
}

// ---------------------------------------------------------------------------
// Cholesky step, de-serialized (R15):
//  - alive set is a PREFIX of e (rightmost-column-first packing) -> slot count
//    is wave-uniform: nG groups of 4 slots, scalar break, NO ballots.
//  - cscR/cscW are distinct static arrays (compile-time via 2x-unrolled k):
//    reads provably never alias writes -> all 8 group loads pipeline.
//  - FMA unconditional (dead vals never consumed); csc write gated by the
//    exact range test key-b1 < 256  <=>  jc == kk+1.  Live-element arithmetic
//    is op-identical to the verified R13 kernel.
// ---------------------------------------------------------------------------
#define CHOL_STEP(CR, CW)                                                     \
    {                                                                         \
        float dk   = CR[kk];                                                  \
        float invd = __builtin_amdgcn_rcpf(dk);                               \
        logacc += __log2f(dk);                                                \
        const unsigned b1 = (unsigned)(kk + 1) << 8;                          \
        const int rem = m - kk;                                               \
        const int nG  = ((rem * (rem + 1)) / 2 + 255) >> 8;                   \
        _Pragma("unroll")                                                     \
        for (int g = 0; g < EMAX / 4; ++g) {                                  \
            if (g >= nG) break;                                               \
            const int t0 = 4 * g;                                             \
            float ci0 = CR[key[t0 + 0] & 255u], cj0 = CR[key[t0 + 0] >> 8];   \
            float ci1 = CR[key[t0 + 1] & 255u], cj1 = CR[key[t0 + 1] >> 8];   \
            float ci2 = CR[key[t0 + 2] & 255u], cj2 = CR[key[t0 + 2] >> 8];   \
            float ci3 = CR[key[t0 + 3] & 255u], cj3 = CR[key[t0 + 3] >> 8];   \
            val[t0 + 0] -= ci0 * cj0 * invd;                                  \
            val[t0 + 1] -= ci1 * cj1 * invd;                                  \
            val[t0 + 2] -= ci2 * cj2 * invd;                                  \
            val[t0 + 3] -= ci3 * cj3 * invd;                                  \
            if (key[t0 + 0] - b1 < 256u) CW[key[t0 + 0] & 255u] = val[t0 + 0];\
            if (key[t0 + 1] - b1 < 256u) CW[key[t0 + 1] & 255u] = val[t0 + 1];\
            if (key[t0 + 2] - b1 < 256u) CW[key[t0 + 2] & 255u] = val[t0 + 2];\
            if (key[t0 + 3] - b1 < 256u) CW[key[t0 + 3] & 255u] = val[t0 + 3];\
        }                                                                     \
        __syncthreads();                                                      \
    }

// ---------------------------------------------------------------------------
// K2 fast: ONE WAVE per sample (R13 structure restored; R14 dual-sample
// interleave reverted -- it halved TLP without creating ILP).
// ---------------------------------------------------------------------------
__global__ __launch_bounds__(64) void k_fast(
    const float* __restrict__ data, const float* __restrict__ mu,
    const float* __restrict__ wgt, const int* __restrict__ src,
    const void* __restrict__ miss, const int* __restrict__ flagarr,
    const float* __restrict__ Q, const float* __restrict__ ldS,
    float* __restrict__ partial, int* __restrict__ ovf_cnt,
    int* __restrict__ ovf_list)
{
    __shared__ float xsh[DD];
    __shared__ float ysh[DD];
    __shared__ int   midx[64];
    __shared__ float csc0[64];
    __shared__ float csc1[64];

    const int i = blockIdx.x, lane = threadIdx.x;
    const int s = src[i];
    const float* Qs = Q + (size_t)s * DD * DD;
    const size_t base = (size_t)i * DD;
    const int j0 = 2 * lane, j1 = 2 * lane + 1;

    // ---- layout flag: OR-reduce flagarr[256] (written by prior dispatch) ----
    int fl = 0;
    #pragma unroll
    for (int t = 0; t < 4; ++t) fl |= flagarr[lane + 64 * t];
    unsigned long long fb1 = __ballot(fl & 1);
    unsigned long long fb2 = __ballot(fl & 2);
    const int f = (fb1 ? 1 : 0) | (fb2 ? 2 : 0);

    // ---- mask decode (uniform branch on detected layout) ----
    bool mmE, mmO;
    if (f & 2) {
        const float* M = (const float*)miss;
        mmE = M[base + j0] != 0.f;  mmO = M[base + j1] != 0.f;
    } else if (f & 1) {
        const unsigned char* M = (const unsigned char*)miss;
        mmE = M[base + j0] != 0;    mmO = M[base + j1] != 0;
    } else {
        const int* M = (const int*)miss;
        mmE = M[base + j0] != 0;    mmO = M[base + j1] != 0;
    }

    unsigned long long bE = __ballot(mmE), bO = __ballot(mmO);
    const int m = __popcll(bE) + __popcll(bO);
    if (m > MFAST) {
        if (lane == 0) { int pos = atomicAdd(ovf_cnt, 1); ovf_list[pos] = i; }
        return;
    }
    unsigned long long lt = (1ull << lane) - 1ull;
    if (mmE) midx[__popcll(bE & lt)] = j0;
    if (mmO) midx[__popcll(bE) + __popcll(bO & lt)] = j1;

    float x0 = mmE ? 0.f : (data[base + j0] - mu[j0]);
    float x1 = mmO ? 0.f : (data[base + j1] - mu[j1]);
    xsh[j0] = x0;
    xsh[j1] = x1;
    __syncthreads();

    // ---- y = Qx by columns: branchless pipelined float2 reads ----
    float y0 = 0.f, y1 = 0.f, z0 = 0.f, z1 = 0.f;
    #pragma unroll 8
    for (int k = 0; k < DD; k += 2) {
        float xk0 = xsh[k], xk1 = xsh[k + 1];
        float2 qa = *(const float2*)(Qs + (size_t)k * DD + j0);
        float2 qb = *(const float2*)(Qs + (size_t)(k + 1) * DD + j0);
        y0 += xk0 * qa.x;  y1 += xk0 * qa.y;
        z0 += xk1 * qb.x;  z1 += xk1 * qb.y;
    }
    y0 += z0;  y1 += z1;
    ysh[j0] = y0;
    ysh[j1] = y1;
    float p = x0 * y0 + x1 * y1;
    for (int o = 32; o; o >>= 1) p += __shfl_down(p, o, 64);   // lane0: x^T Q x
    __syncthreads();   // ysh, midx ready

    // ---- fill register slots DIRECTLY from Q (independent pipelined loads,
    //      column-major from rightmost column) ----
    const int cntT = ((m + 1) * (m + 2)) >> 1;
    unsigned key[EMAX];
    float    val[EMAX];
    #pragma unroll
    for (int t = 0; t < EMAX; ++t) {
        key[t] = 0u; val[t] = 0.f;
        int e = lane + (t << 6);
        if (e < cntT) {
            int q  = tri_row_of(e);            // q = m - col
            int jc = m - q;                    // column
            int ir = jc + (e - ((q * (q + 1)) >> 1));   // row, jc..m
            float v;
            if (ir == m) {
                v = (jc == m) ? 0.f : ysh[midx[jc]];    // border row = u
            } else {
                v = Qs[(size_t)(midx[ir] * DD + midx[jc])];
            }
            key[t] = ((unsigned)jc << 8) | (unsigned)ir;
            val[t] = v;
            if (jc == 0) csc0[ir] = v;         // column 0 seeds buffer 0
        }
    }
    __syncthreads();

    // ---- wave-synchronous factorization: 2x-unrolled k so read/write
    //      buffers are compile-time distinct arrays ----
    float logacc = 0.f;
    {
        int kk = 0;
        while (kk < m) {
            CHOL_STEP(csc0, csc1)
            ++kk;
            if (kk >= m) break;
            CHOL_STEP(csc1, csc0)
            ++kk;
        }
    }

    if (lane == 0) {
        // val[0] = element (m,m) = -u^T Qmm^{-1} u ; quad = p + val[0]
        float ll = -0.5f * ((p + val[0]) + logacc * LN2F + ldS[s]
                            + (float)(DD - m) * LOG_2PI);
        atomicAdd(&partial[i & 63], ll * wgt[i]);
    }
}

// ---------------------------------------------------------------------------
// K tail: single block. (a) drain overflow list (m > MFAST; ~always empty)
// with the verified LDS-triangle Cholesky, (b) reduce partial -> out.
// ---------------------------------------------------------------------------
__global__ __launch_bounds__(128) void k_tail(
    const float* __restrict__ data, const float* __restrict__ mu,
    const float* __restrict__ wgt, const int* __restrict__ src,
    const void* __restrict__ miss, const int* __restrict__ flagarr,
    const float* __restrict__ Q, const float* __restrict__ ldS,
    float* __restrict__ partial, const int* __restrict__ ovf_cnt,
    const int* __restrict__ ovf_list, float* __restrict__ out)
{
    __shared__ __align__(16) float xsh[DD];
    __shared__ float ysh[DD];
    __shared__ int   midx[DD];
    __shared__ float cscv[DD + 1];
    __shared__ float tri[(DD + 1) * (DD + 2) / 2];
    __shared__ float bc[2];
    __shared__ float red[2];
    __shared__ int   sh_m;
    __shared__ int   sh_f;

    const int tid = threadIdx.x;
    if (tid == 0) sh_f = 0;
    __syncthreads();
    {
        int fl = flagarr[tid] | flagarr[tid + 128];
        if (fl) atomicOr(&sh_f, fl);
    }
    __syncthreads();
    const int f = sh_f;

    const int novf = *ovf_cnt;
    for (int j = 0; j < novf; ++j) {
        const int i = ovf_list[j];
        if (tid == 0) sh_m = 0;
        __syncthreads();

        const int s = src[i];
        const float* Qs = Q + (size_t)s * DD * DD;
        const size_t g = (size_t)i * DD + tid;
        bool mm;
        if (f & 2)      mm = ((const float*)miss)[g] != 0.f;
        else if (f & 1) mm = ((const unsigned char*)miss)[g] != 0;
        else            mm = ((const int*)miss)[g] != 0;

        float xv = mm ? 0.f : (data[g] - mu[tid]);
        xsh[tid] = xv;
        if (mm) { int pos = atomicAdd(&sh_m, 1); midx[pos] = tid; }
        __syncthreads();
        const int m = sh_m;

        const float4* qrow = (const float4*)(Qs + (size_t)tid * DD);
        const float4* x4   = (const float4*)xsh;
        float acc = 0.f;
        #pragma unroll 8
        for (int d = 0; d < DD / 4; ++d) {
            float4 q = qrow[d], xx = x4[d];
            acc += q.x * xx.x + q.y * xx.y + q.z * xx.z + q.w * xx.w;
        }
        ysh[tid] = acc;
        float pp = xv * acc;
        for (int o = 32; o; o >>= 1) pp += __shfl_down(pp, o, 64);
        if ((tid & 63) == 0) red[tid >> 6] = pp;
        __syncthreads();

        const int cntA = (m * (m + 1)) >> 1;
        for (int e = tid; e < cntA; e += 128) {
            int a = tri_row_of(e);
            int b = e - ((a * (a + 1)) >> 1);
            tri[e] = Qs[(size_t)midx[a] * DD + midx[b]];
        }
        for (int b = tid; b < m; b += 128) tri[cntA + b] = ysh[midx[b]];
        if (tid == 0) tri[cntA + m] = 0.f;
        __syncthreads();

        float logacc = 0.f;
        if (m > 0) {
            if (tid == 0) {
                float d0 = tri[0];
                bc[1] = d0;
                float sq = sqrtf(d0);
                bc[0] = 1.f / sq;
                tri[0] = sq;
            }
            __syncthreads();
            for (int k = 0; k < m; ++k) {
                float inv = bc[0];
                if (tid == 0) logacc += logf(bc[1]);
                for (int ii = k + 1 + tid; ii <= m; ii += 128) {
                    int off = (ii * (ii + 1)) >> 1;
                    float v = tri[off + k] * inv;
                    tri[off + k] = v;
                    cscv[ii] = v;
                }
                __syncthreads();
                int qn  = m - k;
                int cnt = (qn * (qn + 1)) >> 1;
                for (int e = tid; e < cnt; e += 128) {
                    int ri = tri_row_of(e);
                    int rj = e - ((ri * (ri + 1)) >> 1);
                    int ii = k + 1 + ri, jj = k + 1 + rj;
                    int off = (ii * (ii + 1)) >> 1;
                    float v = tri[off + jj] - cscv[ii] * cscv[jj];
                    if (ii == jj && jj == k + 1 && k + 1 < m) {
                        bc[1] = v;
                        float sq = sqrtf(v);
                        bc[0] = 1.f / sq;
                        tri[off + jj] = sq;
                    } else {
                        tri[off + jj] = v;
                    }
                }
                __syncthreads();
            }
        }

        if (tid == 0) {
            float quad2 = (m > 0) ? -tri[cntA + m] : 0.f;
            float quad1 = red[0] + red[1];
            float ll = -0.5f * ((quad1 - quad2) + logacc + ldS[s]
                                + (float)(DD - m) * LOG_2PI);
            atomicAdd(&partial[i & 63], ll * wgt[i]);
        }
        __syncthreads();
    }

    __syncthreads();
    if (tid < 64) {
        float v = partial[tid];
        for (int o = 32; o; o >>= 1) v += __shfl_down(v, o, 64);
        if (tid == 0) out[0] = v;
    }
}

// ---------------------------------------------------------------------------
extern "C" void kernel_launch(void* const* d_in, const int* in_sizes, int n_in,
                              void* d_out, int out_size, void* d_ws, size_t ws_size,
                              hipStream_t stream)
{
    const float* data = (const float*)d_in[0];
    const float* W    = (const float*)d_in[1];
    const float* ls2  = (const float*)d_in[2];
    const float* mu   = (const float*)d_in[3];
    const float* wgt  = (const float*)d_in[4];
    const int*   src  = (const int*)d_in[5];
    const void*  miss = (const void*)d_in[6];
    float* out = (float*)d_out;

    float* Q        = (float*)d_ws;                    // 131072 floats
    float* ldS      = Q + (size_t)NSRC * DD * DD;      // 8
    float* partial  = ldS + NSRC;                      // 64
    int*   flagarr  = (int*)(partial + 64);            // 256
    int*   ovf_cnt  = flagarr + 256;                   // 1
    int*   ovf_list = ovf_cnt + 1;                     // 4096

    const int n       = in_sizes[0] / DD;              // 4096 samples
    const int n_words = (n * DD) / 4;                  // 131072

    hipLaunchKernelGGL(k_precompute, dim3(NSRC * 32), dim3(128), 0, stream,
                       W, ls2, (const unsigned int*)miss, n_words,
                       Q, ldS, flagarr, partial, ovf_cnt);
    hipLaunchKernelGGL(k_fast, dim3(n), dim3(64), 0, stream,
                       data, mu, wgt, src, miss, flagarr, Q, ldS,
                       partial, ovf_cnt, ovf_list);
    hipLaunchKernelGGL(k_tail, dim3(1), dim3(128), 0, stream,
                       data, mu, wgt, src, miss, flagarr, Q, ldS,
                       partial, ovf_cnt, ovf_list, out);
}